// Round 5
// baseline (519.320 us; speedup 1.0000x reference)
//
#include <hip/hip_runtime.h>
#include <hip/hip_bf16.h>

#define NROWS 8192
#define DIN   4096
#define DOUT  4096
#define KOUT  16
#define NT    (DIN / 64)   // 64 K-tiles

typedef __attribute__((ext_vector_type(8))) short short8v;
typedef __attribute__((ext_vector_type(4))) float floatx4;

typedef const __attribute__((address_space(1))) void* gas1;
typedef __attribute__((address_space(3))) void* las3;

// ---- ws layout (byte offsets) ----
#define WS_COLMAX   0u          // uint[4096]
#define WS_MASK     16384u      // uchar[4096]
#define WS_IDX      20480u      // int[16]
#define WS_WMAX     32768u      // float[4096]
#define WS_XMAX     49152u      // float[8192]
#define WS_WU       81920u      // float[4096*16]
#define WS_XU       344064u     // float[8192*16]
#define WS_WQ       1048576u    // ushort[4096*4096] bf16
#define WS_XQ       34603008u   // ushort[8192*4096] bf16

// ---------------- K1: column absmax ----------------
__global__ __launch_bounds__(256) void k_colmax(const float* __restrict__ x,
                                                unsigned int* __restrict__ colmax) {
  int col = blockIdx.x * 256 + threadIdx.x;
  size_t r0 = (size_t)blockIdx.y * 128;
  unsigned int m = 0;
  for (int r = 0; r < 128; ++r) {
    unsigned int b = __float_as_uint(x[(r0 + r) * DIN + col]) & 0x7fffffffu;
    m = b > m ? b : m;
  }
  atomicMax(&colmax[col], m);
}

// ---------------- K2: top-16 columns + mask ----------------
__global__ __launch_bounds__(256) void k_topk(const unsigned int* __restrict__ colmax,
                                              int* __restrict__ idx,
                                              unsigned char* __restrict__ mask) {
  __shared__ unsigned long long keys[DIN];
  __shared__ unsigned long long red[256];
  int t = threadIdx.x;
  for (int i = t; i < DIN; i += 256) {
    keys[i] = (((unsigned long long)colmax[i]) << 12) | (unsigned long long)i;
    mask[i] = 0;
  }
  __syncthreads();
  for (int r = 0; r < KOUT; ++r) {
    unsigned long long m = 0;
    for (int i = t; i < DIN; i += 256) { unsigned long long k = keys[i]; m = k > m ? k : m; }
    red[t] = m;
    __syncthreads();
    for (int s = 128; s > 0; s >>= 1) {
      if (t < s) { unsigned long long o = red[t + s]; if (o > red[t]) red[t] = o; }
      __syncthreads();
    }
    if (t == 0) {
      int bi = (int)(red[0] & 0xFFFu);
      idx[r] = bi;
      mask[bi] = 1;
      keys[bi] = 0;
    }
    __syncthreads();
  }
}

// ---------------- K3: quantize W ----------------
__global__ __launch_bounds__(256) void k_quantW(const float* __restrict__ W,
                                                const int* __restrict__ idx,
                                                unsigned short* __restrict__ Wq,
                                                float* __restrict__ w_max,
                                                float* __restrict__ Wu) {
  __shared__ float row[DIN];
  __shared__ float red[256];
  int o = blockIdx.x, t = threadIdx.x;
  const float* Wr = W + (size_t)o * DIN;
  float m = 0.f;
  for (int i = t * 4; i < DIN; i += 1024) {
    float4 v = *(const float4*)(Wr + i);
    row[i+0] = v.x; row[i+1] = v.y; row[i+2] = v.z; row[i+3] = v.w;
    m = fmaxf(m, fmaxf(fmaxf(fabsf(v.x), fabsf(v.y)), fmaxf(fabsf(v.z), fabsf(v.w))));
  }
  red[t] = m;
  __syncthreads();
  for (int s = 128; s > 0; s >>= 1) {
    if (t < s) red[t] = fmaxf(red[t], red[t + s]);
    __syncthreads();
  }
  float mx = red[0];
  float sc = 127.0f / mx;
  unsigned short* Wqr = Wq + (size_t)o * DIN;
  for (int i = t * 4; i < DIN; i += 1024) {
    ushort4 q;
    q.x = (unsigned short)(__float_as_uint(rintf(row[i+0] * sc)) >> 16);
    q.y = (unsigned short)(__float_as_uint(rintf(row[i+1] * sc)) >> 16);
    q.z = (unsigned short)(__float_as_uint(rintf(row[i+2] * sc)) >> 16);
    q.w = (unsigned short)(__float_as_uint(rintf(row[i+3] * sc)) >> 16);
    *(ushort4*)(Wqr + i) = q;
  }
  if (t == 0) w_max[o] = mx;
  if (t < KOUT) {
    float wq = rintf(row[idx[t]] * sc);
    Wu[(size_t)o * KOUT + t] = wq * mx / 127.0f;
  }
}

// ---------------- K4: zero outliers + quantize x ----------------
__global__ __launch_bounds__(256) void k_quantX(const float* __restrict__ x,
                                                const unsigned char* __restrict__ mask,
                                                const int* __restrict__ idx,
                                                unsigned short* __restrict__ Xq,
                                                float* __restrict__ x_max,
                                                float* __restrict__ Xu) {
  __shared__ float row[DIN];
  __shared__ float red[256];
  int r = blockIdx.x, t = threadIdx.x;
  const float* xr = x + (size_t)r * DIN;
  float m = 0.f;
  for (int i = t * 4; i < DIN; i += 1024) {
    float4 v = *(const float4*)(xr + i);
    float a0 = mask[i+0] ? 0.f : v.x;
    float a1 = mask[i+1] ? 0.f : v.y;
    float a2 = mask[i+2] ? 0.f : v.z;
    float a3 = mask[i+3] ? 0.f : v.w;
    row[i+0] = a0; row[i+1] = a1; row[i+2] = a2; row[i+3] = a3;
    m = fmaxf(m, fmaxf(fmaxf(fabsf(a0), fabsf(a1)), fmaxf(fabsf(a2), fabsf(a3))));
  }
  red[t] = m;
  __syncthreads();
  for (int s = 128; s > 0; s >>= 1) {
    if (t < s) red[t] = fmaxf(red[t], red[t + s]);
    __syncthreads();
  }
  float mx = red[0];
  float sc = 127.0f / mx;
  unsigned short* Xqr = Xq + (size_t)r * DIN;
  for (int i = t * 4; i < DIN; i += 1024) {
    ushort4 q;
    q.x = (unsigned short)(__float_as_uint(rintf(row[i+0] * sc)) >> 16);
    q.y = (unsigned short)(__float_as_uint(rintf(row[i+1] * sc)) >> 16);
    q.z = (unsigned short)(__float_as_uint(rintf(row[i+2] * sc)) >> 16);
    q.w = (unsigned short)(__float_as_uint(rintf(row[i+3] * sc)) >> 16);
    *(ushort4*)(Xqr + i) = q;
  }
  if (t == 0) x_max[r] = mx;
  if (t < KOUT) Xu[(size_t)r * KOUT + t] = xr[idx[t]];
}

// ---------------- K5: 256x256 8-phase (2 K-tiles/iter) bf16 MFMA GEMM ----------------
// 8 waves (2M x 4N), BK=64. LDS 128KB: buf0 = even tiles, buf1 = odd tiles (static).
// Stage units (per wave 2 x global_load_lds, block-wide = one half-tile):
//   SA0 = A rows read by RD_A(·,0); SA1 = rows for RD_A(·,1)
//   SB0 = B rows read by RD_B(·,0); SB1 = rows for RD_B(·,1)
// Quadrant order per tile: (0,0),(0,1),(1,1),(1,0) -> slot deaths ph2,ph3,ph4,ph4.
// Stage schedule (iter i; t0=2i,t1=2i+1 consumed; t2,t3 prefetched):
//   ph1 SB0(b1,t1)  ph2 SA1(b1,t1)  ph3 SA0(b0,t2)  ph4 SB1(b0,t2)+vmcnt(4)
//   ph5 SA1(b0,t2)  ph6 SB0(b0,t2)  ph7 SA0(b1,t3)  ph8 SB1(b1,t3)+vmcnt(4)
// vmcnt(4)@ph4 covers ph1-2 stages (read ph5-8); @ph8 covers ph3-6 (read next ph1-4).
#define VMWAIT(n) asm volatile("s_waitcnt vmcnt(" #n ")" ::: "memory")
#define BAR() __builtin_amdgcn_s_barrier()

__global__ __launch_bounds__(512, 2) void k_gemm(const unsigned short* __restrict__ Xq,
                                                 const unsigned short* __restrict__ Wq,
                                                 const float* __restrict__ x_max,
                                                 const float* __restrict__ w_max,
                                                 const float* __restrict__ Xu,
                                                 const float* __restrict__ Wu,
                                                 const float* __restrict__ bias,
                                                 float* __restrict__ out) {
  extern __shared__ char smem[];
  unsigned short* sA = (unsigned short*)smem;   // [2][256][64]
  unsigned short* sB = sA + 2 * 256 * 64;       // [2][256][64]

  int t = threadIdx.x;
  int wid = t >> 6, l = t & 63;
  int wm = wid >> 2, wn = wid & 3;       // wave tile: rows wm*128+[0,128), cols wn*64+[0,64)
  int lane_r = l & 15, lane_k = l >> 4;
  int sw = lane_r & 7;
  int l3 = l >> 3;
  int swc = ((l & 7) ^ (l3 & 7)) * 8;    // pre-swizzled source chunk (elems)
  int bh = wn >> 1;                      // B half this wave stages
  int p8 = ((wm << 1) | (wn & 1)) * 8;

  // XCD-aware bijective swizzle: nwg = 32 Mtiles * 16 Ntiles = 512, %8==0
  int bid = blockIdx.x;
  int wg = (bid & 7) * 64 + (bid >> 3);
  int bM = wg >> 4, bN = wg & 15;

  const unsigned short* gA = Xq + (size_t)(bM * 256 + wm * 128 + wn * 16 + l3) * DIN + swc;
  const unsigned short* gB = Wq + (size_t)(bN * 256 + bh * 128 + p8 + l3) * DIN + swc;
  int dA0 = (wm * 128 + wn * 16) * 64;
  int dB0 = (bh * 128 + p8) * 64;

  floatx4 acc[8][4];
  #pragma unroll
  for (int i = 0; i < 8; ++i)
    #pragma unroll
    for (int j = 0; j < 4; ++j)
      acc[i][j] = (floatx4){0.f, 0.f, 0.f, 0.f};

#define GL_A(koff, roff, bufn) \
  __builtin_amdgcn_global_load_lds((gas1)(gA + (size_t)(roff) * DIN + (koff)), \
                                   (las3)(sA + (bufn) * 16384 + dA0 + (roff) * 64), 16, 0, 0)
#define GL_B(koff, roff, bufn) \
  __builtin_amdgcn_global_load_lds((gas1)(gB + (size_t)(roff) * DIN + (koff)), \
                                   (las3)(sB + (bufn) * 16384 + dB0 + (roff) * 64), 16, 0, 0)
#define SA0(ko, bufn) do { GL_A(ko, 0, bufn); GL_A(ko, 8, bufn); } while (0)
#define SA1(ko, bufn) do { GL_A(ko, 64, bufn); GL_A(ko, 72, bufn); } while (0)
#define SB0(ko, bufn) do { GL_B(ko, 0, bufn); GL_B(ko, 64, bufn); } while (0)
#define SB1(ko, bufn) do { GL_B(ko, 32, bufn); GL_B(ko, 96, bufn); } while (0)

  const unsigned short* sA0p = sA;            // buf0 A
  const unsigned short* sA1p = sA + 16384;    // buf1 A
  const unsigned short* sB0p = sB;            // buf0 B
  const unsigned short* sB1p = sB + 16384;    // buf1 B

  short8v a_[4][2], b_[2][2];

#define RD_A(P, MH) \
  _Pragma("unroll") \
  for (int mi = 0; mi < 4; ++mi) \
    _Pragma("unroll") \
    for (int kk = 0; kk < 2; ++kk) \
      a_[mi][kk] = *(const short8v*)((P) + (wm * 128 + (MH) * 64 + mi * 16 + lane_r) * 64 + \
                                     (((kk * 4 + lane_k) ^ sw) * 8));
#define RD_B(P, NH) \
  _Pragma("unroll") \
  for (int ni = 0; ni < 2; ++ni) \
    _Pragma("unroll") \
    for (int kk = 0; kk < 2; ++kk) \
      b_[ni][kk] = *(const short8v*)((P) + (wn * 64 + (NH) * 32 + ni * 16 + lane_r) * 64 + \
                                     (((kk * 4 + lane_k) ^ sw) * 8));
#define MFMA16(MH, NH) \
  __builtin_amdgcn_s_setprio(1); \
  _Pragma("unroll") \
  for (int mi = 0; mi < 4; ++mi) \
    _Pragma("unroll") \
    for (int ni = 0; ni < 2; ++ni) \
      _Pragma("unroll") \
      for (int kk = 0; kk < 2; ++kk) \
        acc[(MH) * 4 + mi][(NH) * 2 + ni] = \
          __builtin_amdgcn_mfma_f32_16x16x32_bf16(a_[mi][kk], b_[ni][kk], \
                                                  acc[(MH) * 4 + mi][(NH) * 2 + ni], 0, 0, 0); \
  __builtin_amdgcn_s_setprio(0);

  // prologue: t0 fully (8 loads) + t1's SA0,SB1 (4 loads); wait -> t0 resident
  SA0(0, 0); SB1(0, 0); SA1(0, 0); SB0(0, 0);
  SA0(64, 1); SB1(64, 1);
  VMWAIT(4);
  BAR();

  for (int i = 0; i < NT / 2 - 1; ++i) {
    size_t k1 = (size_t)(2 * i + 1) * 64;
    size_t k2 = (size_t)(2 * i + 2) * 64;
    size_t k3 = (size_t)(2 * i + 3) * 64;
    // ph1 [buf0 Q(0,0)]
    RD_A(sA0p, 0); RD_B(sB0p, 0);
    SB0(k1, 1);
    BAR(); MFMA16(0, 0); BAR();
    // ph2 [buf0 Q(0,1)]
    RD_B(sB0p, 1);
    SA1(k1, 1);
    BAR(); MFMA16(0, 1); BAR();
    // ph3 [buf0 Q(1,1)]
    RD_A(sA0p, 1);
    SA0(k2, 0);
    BAR(); MFMA16(1, 1); BAR();
    // ph4 [buf0 Q(1,0)]
    RD_B(sB0p, 0);
    SB1(k2, 0);
    BAR(); MFMA16(1, 0); VMWAIT(4); BAR();
    // ph5 [buf1 Q(0,0)]
    RD_A(sA1p, 0); RD_B(sB1p, 0);
    SA1(k2, 0);
    BAR(); MFMA16(0, 0); BAR();
    // ph6 [buf1 Q(0,1)]
    RD_B(sB1p, 1);
    SB0(k2, 0);
    BAR(); MFMA16(0, 1); BAR();
    // ph7 [buf1 Q(1,1)]
    RD_A(sA1p, 1);
    SA0(k3, 1);
    BAR(); MFMA16(1, 1); BAR();
    // ph8 [buf1 Q(1,0)]
    RD_B(sB1p, 0);
    SB1(k3, 1);
    BAR(); MFMA16(1, 0); VMWAIT(4); BAR();
  }
  { // peeled final double-tile (t0 = NT-2 resident; t1 = NT-1 needs SB0,SA1)
    size_t k1 = (size_t)(NT - 1) * 64;
    RD_A(sA0p, 0); RD_B(sB0p, 0);
    SB0(k1, 1);
    BAR(); MFMA16(0, 0); BAR();
    RD_B(sB0p, 1);
    SA1(k1, 1);
    BAR(); MFMA16(0, 1); BAR();
    RD_A(sA0p, 1);
    BAR(); MFMA16(1, 1); BAR();
    RD_B(sB0p, 0);
    BAR(); MFMA16(1, 0); VMWAIT(0); BAR();
    RD_A(sA1p, 0); RD_B(sB1p, 0);
    BAR(); MFMA16(0, 0); BAR();
    RD_B(sB1p, 1);
    BAR(); MFMA16(0, 1); BAR();
    RD_A(sA1p, 1);
    BAR(); MFMA16(1, 1); BAR();
    RD_B(sB1p, 0);
    BAR(); MFMA16(1, 0); BAR();
  }

  // ---- epilogue: stage Xu/Wu/scales/bias tiles into (reused) LDS ----
  float* eXu = (float*)smem;            // [256][17] padded
  float* eWu = eXu + 256 * 17;          // [256][17]
  float* exm = eWu + 256 * 17;          // [256]
  float* ewm = exm + 256;               // [256]
  float* ebs = ewm + 256;               // [256]

  for (int i = t; i < 256 * KOUT; i += 512) {
    int rr = i >> 4, k = i & 15;
    eXu[rr * 17 + k] = Xu[((size_t)(bM * 256 + rr)) * KOUT + k];
    eWu[rr * 17 + k] = Wu[((size_t)(bN * 256 + rr)) * KOUT + k];
  }
  if (t < 256) {
    exm[t] = x_max[bM * 256 + t];
    ewm[t] = w_max[bN * 256 + t];
    ebs[t] = bias[bN * 256 + t];
  }
  __syncthreads();

  #pragma unroll
  for (int mi = 0; mi < 8; ++mi) {
    #pragma unroll
    for (int i2 = 0; i2 < 4; ++i2) {
      int rl = wm * 128 + mi * 16 + lane_k * 4 + i2;   // C/D: row=(l>>4)*4+reg
      float xm = exm[rl];
      float xu[KOUT];
      #pragma unroll
      for (int k = 0; k < KOUT; ++k) xu[k] = eXu[rl * 17 + k];
      size_t orow = ((size_t)(bM * 256 + rl)) * DOUT + (size_t)bN * 256;
      #pragma unroll
      for (int ni = 0; ni < 4; ++ni) {
        int cl = wn * 64 + ni * 16 + lane_r;            // C/D: col=l&15
        float rq = acc[mi][ni][i2];
        float v = (float)(_Float16)(rq / 16129.0f) * (xm * ewm[cl]);
        float dot = 0.f;
        #pragma unroll
        for (int k = 0; k < KOUT; ++k) dot = fmaf(xu[k], eWu[cl * 17 + k], dot);
        out[orow + cl] = v + dot + ebs[cl];
      }
    }
  }
}

extern "C" void kernel_launch(void* const* d_in, const int* in_sizes, int n_in,
                              void* d_out, int out_size, void* d_ws, size_t ws_size,
                              hipStream_t stream) {
  const float* x    = (const float*)d_in[0];
  const float* W    = (const float*)d_in[1];
  const float* bias = (const float*)d_in[2];
  float* out = (float*)d_out;
  char* ws = (char*)d_ws;

  unsigned int*   colmax = (unsigned int*)(ws + WS_COLMAX);
  unsigned char*  mask   = (unsigned char*)(ws + WS_MASK);
  int*            idx    = (int*)(ws + WS_IDX);
  float*          w_max  = (float*)(ws + WS_WMAX);
  float*          x_max  = (float*)(ws + WS_XMAX);
  float*          Wu     = (float*)(ws + WS_WU);
  float*          Xu     = (float*)(ws + WS_XU);
  unsigned short* Wq     = (unsigned short*)(ws + WS_WQ);
  unsigned short* Xq     = (unsigned short*)(ws + WS_XQ);

  hipFuncSetAttribute((const void*)k_gemm, hipFuncAttributeMaxDynamicSharedMemorySize, 131072);

  hipMemsetAsync(colmax, 0, DIN * sizeof(unsigned int), stream);
  k_colmax<<<dim3(DIN / 256, NROWS / 128), 256, 0, stream>>>(x, colmax);
  k_topk<<<1, 256, 0, stream>>>(colmax, idx, mask);
  k_quantW<<<DOUT, 256, 0, stream>>>(W, idx, Wq, w_max, Wu);
  k_quantX<<<NROWS, 256, 0, stream>>>(x, mask, idx, Xq, x_max, Xu);
  k_gemm<<<512, 512, 131072, stream>>>(Xq, Wq, x_max, w_max, Xu, Wu, bias, out);
}

// Round 6
// 509.298 us; speedup vs baseline: 1.0197x; 1.0197x over previous
//
#include <hip/hip_runtime.h>
#include <hip/hip_bf16.h>

#define NROWS 8192
#define DIN   4096
#define DOUT  4096
#define KOUT  16
#define NT    (DIN / 64)   // 64 K-tiles

typedef __attribute__((ext_vector_type(8))) short short8v;
typedef __attribute__((ext_vector_type(4))) float floatx4;

typedef const __attribute__((address_space(1))) void* gas1;
typedef __attribute__((address_space(3))) void* las3;

// ---- ws layout (byte offsets) ----
#define WS_COLMAX   0u          // uint[4096]
#define WS_MASK     16384u      // uchar[4096]
#define WS_IDX      20480u      // int[16]
#define WS_WMAX     32768u      // float[4096]
#define WS_XMAX     49152u      // float[8192]
#define WS_WU       81920u      // float[4096*16]
#define WS_XU       344064u     // float[8192*16]
#define WS_WQ       1048576u    // ushort[4096*4096] bf16
#define WS_XQ       34603008u   // ushort[8192*4096] bf16

// ---------------- K1: column absmax ----------------
__global__ __launch_bounds__(256) void k_colmax(const float* __restrict__ x,
                                                unsigned int* __restrict__ colmax) {
  int col = blockIdx.x * 256 + threadIdx.x;
  size_t r0 = (size_t)blockIdx.y * 128;
  unsigned int m = 0;
  for (int r = 0; r < 128; ++r) {
    unsigned int b = __float_as_uint(x[(r0 + r) * DIN + col]) & 0x7fffffffu;
    m = b > m ? b : m;
  }
  atomicMax(&colmax[col], m);
}

// ---------------- K2: top-16 columns + mask ----------------
__global__ __launch_bounds__(256) void k_topk(const unsigned int* __restrict__ colmax,
                                              int* __restrict__ idx,
                                              unsigned char* __restrict__ mask) {
  __shared__ unsigned long long keys[DIN];
  __shared__ unsigned long long red[256];
  int t = threadIdx.x;
  for (int i = t; i < DIN; i += 256) {
    keys[i] = (((unsigned long long)colmax[i]) << 12) | (unsigned long long)i;
    mask[i] = 0;
  }
  __syncthreads();
  for (int r = 0; r < KOUT; ++r) {
    unsigned long long m = 0;
    for (int i = t; i < DIN; i += 256) { unsigned long long k = keys[i]; m = k > m ? k : m; }
    red[t] = m;
    __syncthreads();
    for (int s = 128; s > 0; s >>= 1) {
      if (t < s) { unsigned long long o = red[t + s]; if (o > red[t]) red[t] = o; }
      __syncthreads();
    }
    if (t == 0) {
      int bi = (int)(red[0] & 0xFFFu);
      idx[r] = bi;
      mask[bi] = 1;
      keys[bi] = 0;
    }
    __syncthreads();
  }
}

// ---------------- K3: quantize W ----------------
__global__ __launch_bounds__(256) void k_quantW(const float* __restrict__ W,
                                                const int* __restrict__ idx,
                                                unsigned short* __restrict__ Wq,
                                                float* __restrict__ w_max,
                                                float* __restrict__ Wu) {
  __shared__ float row[DIN];
  __shared__ float red[256];
  int o = blockIdx.x, t = threadIdx.x;
  const float* Wr = W + (size_t)o * DIN;
  float m = 0.f;
  for (int i = t * 4; i < DIN; i += 1024) {
    float4 v = *(const float4*)(Wr + i);
    row[i+0] = v.x; row[i+1] = v.y; row[i+2] = v.z; row[i+3] = v.w;
    m = fmaxf(m, fmaxf(fmaxf(fabsf(v.x), fabsf(v.y)), fmaxf(fabsf(v.z), fabsf(v.w))));
  }
  red[t] = m;
  __syncthreads();
  for (int s = 128; s > 0; s >>= 1) {
    if (t < s) red[t] = fmaxf(red[t], red[t + s]);
    __syncthreads();
  }
  float mx = red[0];
  float sc = 127.0f / mx;
  unsigned short* Wqr = Wq + (size_t)o * DIN;
  for (int i = t * 4; i < DIN; i += 1024) {
    ushort4 q;
    q.x = (unsigned short)(__float_as_uint(rintf(row[i+0] * sc)) >> 16);
    q.y = (unsigned short)(__float_as_uint(rintf(row[i+1] * sc)) >> 16);
    q.z = (unsigned short)(__float_as_uint(rintf(row[i+2] * sc)) >> 16);
    q.w = (unsigned short)(__float_as_uint(rintf(row[i+3] * sc)) >> 16);
    *(ushort4*)(Wqr + i) = q;
  }
  if (t == 0) w_max[o] = mx;
  if (t < KOUT) {
    float wq = rintf(row[idx[t]] * sc);
    Wu[(size_t)o * KOUT + t] = wq * mx / 127.0f;
  }
}

// ---------------- K4: zero outliers + quantize x ----------------
__global__ __launch_bounds__(256) void k_quantX(const float* __restrict__ x,
                                                const unsigned char* __restrict__ mask,
                                                const int* __restrict__ idx,
                                                unsigned short* __restrict__ Xq,
                                                float* __restrict__ x_max,
                                                float* __restrict__ Xu) {
  __shared__ float row[DIN];
  __shared__ float red[256];
  int r = blockIdx.x, t = threadIdx.x;
  const float* xr = x + (size_t)r * DIN;
  float m = 0.f;
  for (int i = t * 4; i < DIN; i += 1024) {
    float4 v = *(const float4*)(xr + i);
    float a0 = mask[i+0] ? 0.f : v.x;
    float a1 = mask[i+1] ? 0.f : v.y;
    float a2 = mask[i+2] ? 0.f : v.z;
    float a3 = mask[i+3] ? 0.f : v.w;
    row[i+0] = a0; row[i+1] = a1; row[i+2] = a2; row[i+3] = a3;
    m = fmaxf(m, fmaxf(fmaxf(fabsf(a0), fabsf(a1)), fmaxf(fabsf(a2), fabsf(a3))));
  }
  red[t] = m;
  __syncthreads();
  for (int s = 128; s > 0; s >>= 1) {
    if (t < s) red[t] = fmaxf(red[t], red[t + s]);
    __syncthreads();
  }
  float mx = red[0];
  float sc = 127.0f / mx;
  unsigned short* Xqr = Xq + (size_t)r * DIN;
  for (int i = t * 4; i < DIN; i += 1024) {
    ushort4 q;
    q.x = (unsigned short)(__float_as_uint(rintf(row[i+0] * sc)) >> 16);
    q.y = (unsigned short)(__float_as_uint(rintf(row[i+1] * sc)) >> 16);
    q.z = (unsigned short)(__float_as_uint(rintf(row[i+2] * sc)) >> 16);
    q.w = (unsigned short)(__float_as_uint(rintf(row[i+3] * sc)) >> 16);
    *(ushort4*)(Xqr + i) = q;
  }
  if (t == 0) x_max[r] = mx;
  if (t < KOUT) Xu[(size_t)r * KOUT + t] = xr[idx[t]];
}

// ---------------- K5: 256x256 8-phase (2 K-tiles/iter) bf16 MFMA GEMM ----------------
// Same schedule/ledger as R5; LDS reads converted to inline-asm ds_read_b128 so the
// compiler's LDS-DMA alias tracking cannot insert vmcnt(0) drains before them.
// Waits are fully manual: lgkmcnt(0)+sched_barrier(0) after BAR1 (rule #18);
// counted vmcnt(4) at phases 4/8 only. Address = 4 VGPR bases + compile-time
// offset immediates (buf*32768 + half*{8192|4096} + frag*2048 bytes).
#define VMWAIT(n) asm volatile("s_waitcnt vmcnt(" #n ")" ::: "memory")
#define BAR() __builtin_amdgcn_s_barrier()
#define WAITLDS() do { asm volatile("s_waitcnt lgkmcnt(0)" ::: "memory"); \
                       __builtin_amdgcn_sched_barrier(0); } while (0)
#define DSR(dst, base, imm) \
  asm volatile("ds_read_b128 %0, %1 offset:%c2" : "=v"(dst) : "v"(base), "n"(imm))

__global__ __launch_bounds__(512, 2) void k_gemm(const unsigned short* __restrict__ Xq,
                                                 const unsigned short* __restrict__ Wq,
                                                 const float* __restrict__ x_max,
                                                 const float* __restrict__ w_max,
                                                 const float* __restrict__ Xu,
                                                 const float* __restrict__ Wu,
                                                 const float* __restrict__ bias,
                                                 float* __restrict__ out) {
  extern __shared__ char smem[];
  unsigned short* sA = (unsigned short*)smem;   // [2][256][64]
  unsigned short* sB = sA + 2 * 256 * 64;       // [2][256][64]

  int t = threadIdx.x;
  int wid = t >> 6, l = t & 63;
  int wm = wid >> 2, wn = wid & 3;       // wave tile: rows wm*128+[0,128), cols wn*64+[0,64)
  int lane_r = l & 15, lane_k = l >> 4;
  int sw = lane_r & 7;
  int l3 = l >> 3;
  int swc = ((l & 7) ^ (l3 & 7)) * 8;    // pre-swizzled source chunk (elems)
  int bh = wn >> 1;                      // B half this wave stages
  int p8 = ((wm << 1) | (wn & 1)) * 8;

  // XCD-aware bijective swizzle: nwg = 32 Mtiles * 16 Ntiles = 512, %8==0
  int bid = blockIdx.x;
  int wg = (bid & 7) * 64 + (bid >> 3);
  int bM = wg >> 4, bN = wg & 15;

  const unsigned short* gA = Xq + (size_t)(bM * 256 + wm * 128 + wn * 16 + l3) * DIN + swc;
  const unsigned short* gB = Wq + (size_t)(bN * 256 + bh * 128 + p8 + l3) * DIN + swc;
  int dA0 = (wm * 128 + wn * 16) * 64;
  int dB0 = (bh * 128 + p8) * 64;

  // ds_read base addresses (byte LDS offsets), kk=0/1 variants; everything else
  // is folded into the offset immediate.
  unsigned aA0 = (unsigned)(size_t)(las3)(sA + (wm * 128 + lane_r) * 64 + ((lane_k ^ sw) * 8));
  unsigned aA1 = (unsigned)(size_t)(las3)(sA + (wm * 128 + lane_r) * 64 + (((4 + lane_k) ^ sw) * 8));
  unsigned aB0 = (unsigned)(size_t)(las3)(sB + (wn * 64 + lane_r) * 64 + ((lane_k ^ sw) * 8));
  unsigned aB1 = (unsigned)(size_t)(las3)(sB + (wn * 64 + lane_r) * 64 + (((4 + lane_k) ^ sw) * 8));

  floatx4 acc[8][4];
  #pragma unroll
  for (int i = 0; i < 8; ++i)
    #pragma unroll
    for (int j = 0; j < 4; ++j)
      acc[i][j] = (floatx4){0.f, 0.f, 0.f, 0.f};

#define GL_A(koff, roff, bufn) \
  __builtin_amdgcn_global_load_lds((gas1)(gA + (size_t)(roff) * DIN + (koff)), \
                                   (las3)(sA + (bufn) * 16384 + dA0 + (roff) * 64), 16, 0, 0)
#define GL_B(koff, roff, bufn) \
  __builtin_amdgcn_global_load_lds((gas1)(gB + (size_t)(roff) * DIN + (koff)), \
                                   (las3)(sB + (bufn) * 16384 + dB0 + (roff) * 64), 16, 0, 0)
#define SA0(ko, bufn) do { GL_A(ko, 0, bufn); GL_A(ko, 8, bufn); } while (0)
#define SA1(ko, bufn) do { GL_A(ko, 64, bufn); GL_A(ko, 72, bufn); } while (0)
#define SB0(ko, bufn) do { GL_B(ko, 0, bufn); GL_B(ko, 64, bufn); } while (0)
#define SB1(ko, bufn) do { GL_B(ko, 32, bufn); GL_B(ko, 96, bufn); } while (0)

  short8v a_[4][2], b_[2][2];

#define RD_A(BUF, MH) do { \
  DSR(a_[0][0], aA0, (BUF) * 32768 + (MH) * 8192 + 0);    \
  DSR(a_[0][1], aA1, (BUF) * 32768 + (MH) * 8192 + 0);    \
  DSR(a_[1][0], aA0, (BUF) * 32768 + (MH) * 8192 + 2048); \
  DSR(a_[1][1], aA1, (BUF) * 32768 + (MH) * 8192 + 2048); \
  DSR(a_[2][0], aA0, (BUF) * 32768 + (MH) * 8192 + 4096); \
  DSR(a_[2][1], aA1, (BUF) * 32768 + (MH) * 8192 + 4096); \
  DSR(a_[3][0], aA0, (BUF) * 32768 + (MH) * 8192 + 6144); \
  DSR(a_[3][1], aA1, (BUF) * 32768 + (MH) * 8192 + 6144); \
} while (0)
#define RD_B(BUF, NH) do { \
  DSR(b_[0][0], aB0, (BUF) * 32768 + (NH) * 4096 + 0);    \
  DSR(b_[0][1], aB1, (BUF) * 32768 + (NH) * 4096 + 0);    \
  DSR(b_[1][0], aB0, (BUF) * 32768 + (NH) * 4096 + 2048); \
  DSR(b_[1][1], aB1, (BUF) * 32768 + (NH) * 4096 + 2048); \
} while (0)

#define MFMA16(MH, NH) \
  __builtin_amdgcn_s_setprio(1); \
  _Pragma("unroll") \
  for (int mi = 0; mi < 4; ++mi) \
    _Pragma("unroll") \
    for (int ni = 0; ni < 2; ++ni) \
      _Pragma("unroll") \
      for (int kk = 0; kk < 2; ++kk) \
        acc[(MH) * 4 + mi][(NH) * 2 + ni] = \
          __builtin_amdgcn_mfma_f32_16x16x32_bf16(a_[mi][kk], b_[ni][kk], \
                                                  acc[(MH) * 4 + mi][(NH) * 2 + ni], 0, 0, 0); \
  __builtin_amdgcn_s_setprio(0);

  // prologue: t0 fully (8 loads) + t1's SA0,SB1 (4 loads); wait -> t0 resident
  SA0(0, 0); SB1(0, 0); SA1(0, 0); SB0(0, 0);
  SA0(64, 1); SB1(64, 1);
  VMWAIT(4);
  BAR();

  for (int i = 0; i < NT / 2 - 1; ++i) {
    size_t k1 = (size_t)(2 * i + 1) * 64;
    size_t k2 = (size_t)(2 * i + 2) * 64;
    size_t k3 = (size_t)(2 * i + 3) * 64;
    // ph1 [buf0 Q(0,0)]
    RD_A(0, 0); RD_B(0, 0);
    SB0(k1, 1);
    BAR(); WAITLDS(); MFMA16(0, 0); BAR();
    // ph2 [buf0 Q(0,1)]
    RD_B(0, 1);
    SA1(k1, 1);
    BAR(); WAITLDS(); MFMA16(0, 1); BAR();
    // ph3 [buf0 Q(1,1)]
    RD_A(0, 1);
    SA0(k2, 0);
    BAR(); WAITLDS(); MFMA16(1, 1); BAR();
    // ph4 [buf0 Q(1,0)]
    RD_B(0, 0);
    SB1(k2, 0);
    BAR(); WAITLDS(); MFMA16(1, 0);
    __builtin_amdgcn_sched_barrier(0); VMWAIT(4); BAR();
    // ph5 [buf1 Q(0,0)]
    RD_A(1, 0); RD_B(1, 0);
    SA1(k2, 0);
    BAR(); WAITLDS(); MFMA16(0, 0); BAR();
    // ph6 [buf1 Q(0,1)]
    RD_B(1, 1);
    SB0(k2, 0);
    BAR(); WAITLDS(); MFMA16(0, 1); BAR();
    // ph7 [buf1 Q(1,1)]
    RD_A(1, 1);
    SA0(k3, 1);
    BAR(); WAITLDS(); MFMA16(1, 1); BAR();
    // ph8 [buf1 Q(1,0)]
    RD_B(1, 0);
    SB1(k3, 1);
    BAR(); WAITLDS(); MFMA16(1, 0);
    __builtin_amdgcn_sched_barrier(0); VMWAIT(4); BAR();
  }
  { // peeled final double-tile (t0 = NT-2 resident; t1 = NT-1 needs SB0,SA1)
    size_t k1 = (size_t)(NT - 1) * 64;
    RD_A(0, 0); RD_B(0, 0);
    SB0(k1, 1);
    BAR(); WAITLDS(); MFMA16(0, 0); BAR();
    RD_B(0, 1);
    SA1(k1, 1);
    BAR(); WAITLDS(); MFMA16(0, 1); BAR();
    RD_A(0, 1);
    BAR(); WAITLDS(); MFMA16(1, 1); BAR();
    RD_B(0, 0);
    BAR(); WAITLDS(); MFMA16(1, 0);
    __builtin_amdgcn_sched_barrier(0); VMWAIT(0); BAR();
    RD_A(1, 0); RD_B(1, 0);
    BAR(); WAITLDS(); MFMA16(0, 0); BAR();
    RD_B(1, 1);
    BAR(); WAITLDS(); MFMA16(0, 1); BAR();
    RD_A(1, 1);
    BAR(); WAITLDS(); MFMA16(1, 1); BAR();
    RD_B(1, 0);
    BAR(); WAITLDS(); MFMA16(1, 0); BAR();
  }

  // ---- epilogue: stage Xu/Wu/scales/bias tiles into (reused) LDS ----
  float* eXu = (float*)smem;            // [256][17] padded
  float* eWu = eXu + 256 * 17;          // [256][17]
  float* exm = eWu + 256 * 17;          // [256]
  float* ewm = exm + 256;               // [256]
  float* ebs = ewm + 256;               // [256]

  __syncthreads();
  for (int i = t; i < 256 * KOUT; i += 512) {
    int rr = i >> 4, k = i & 15;
    eXu[rr * 17 + k] = Xu[((size_t)(bM * 256 + rr)) * KOUT + k];
    eWu[rr * 17 + k] = Wu[((size_t)(bN * 256 + rr)) * KOUT + k];
  }
  if (t < 256) {
    exm[t] = x_max[bM * 256 + t];
    ewm[t] = w_max[bN * 256 + t];
    ebs[t] = bias[bN * 256 + t];
  }
  __syncthreads();

  #pragma unroll
  for (int mi = 0; mi < 8; ++mi) {
    #pragma unroll
    for (int i2 = 0; i2 < 4; ++i2) {
      int rl = wm * 128 + mi * 16 + lane_k * 4 + i2;   // C/D: row=(l>>4)*4+reg
      float xm = exm[rl];
      float xu[KOUT];
      #pragma unroll
      for (int k = 0; k < KOUT; ++k) xu[k] = eXu[rl * 17 + k];
      size_t orow = ((size_t)(bM * 256 + rl)) * DOUT + (size_t)bN * 256;
      #pragma unroll
      for (int ni = 0; ni < 4; ++ni) {
        int cl = wn * 64 + ni * 16 + lane_r;            // C/D: col=l&15
        float rq = acc[mi][ni][i2];
        float v = (float)(_Float16)(rq / 16129.0f) * (xm * ewm[cl]);
        float dot = 0.f;
        #pragma unroll
        for (int k = 0; k < KOUT; ++k) dot = fmaf(xu[k], eWu[cl * 17 + k], dot);
        out[orow + cl] = v + dot + ebs[cl];
      }
    }
  }
}

extern "C" void kernel_launch(void* const* d_in, const int* in_sizes, int n_in,
                              void* d_out, int out_size, void* d_ws, size_t ws_size,
                              hipStream_t stream) {
  const float* x    = (const float*)d_in[0];
  const float* W    = (const float*)d_in[1];
  const float* bias = (const float*)d_in[2];
  float* out = (float*)d_out;
  char* ws = (char*)d_ws;

  unsigned int*   colmax = (unsigned int*)(ws + WS_COLMAX);
  unsigned char*  mask   = (unsigned char*)(ws + WS_MASK);
  int*            idx    = (int*)(ws + WS_IDX);
  float*          w_max  = (float*)(ws + WS_WMAX);
  float*          x_max  = (float*)(ws + WS_XMAX);
  float*          Wu     = (float*)(ws + WS_WU);
  float*          Xu     = (float*)(ws + WS_XU);
  unsigned short* Wq     = (unsigned short*)(ws + WS_WQ);
  unsigned short* Xq     = (unsigned short*)(ws + WS_XQ);

  hipFuncSetAttribute((const void*)k_gemm, hipFuncAttributeMaxDynamicSharedMemorySize, 131072);

  hipMemsetAsync(colmax, 0, DIN * sizeof(unsigned int), stream);
  k_colmax<<<dim3(DIN / 256, NROWS / 128), 256, 0, stream>>>(x, colmax);
  k_topk<<<1, 256, 0, stream>>>(colmax, idx, mask);
  k_quantW<<<DOUT, 256, 0, stream>>>(W, idx, Wq, w_max, Wu);
  k_quantX<<<NROWS, 256, 0, stream>>>(x, mask, idx, Xq, x_max, Xu);
  k_gemm<<<512, 512, 131072, stream>>>(Xq, Wq, x_max, w_max, Xu, Wu, bias, out);
}